// Round 18
// baseline (53.704 us; speedup 1.0000x reference)
//
#include <hip/hip_runtime.h>
#include <math.h>

// Problem constants
#define NB 8      // batch
#define NC 256    // channels
#define NN 1024   // spatial H*W
#define NICH 64   // inter channels

// ws layout (float offsets)
#define WS_AQ    0        // [256]
#define WS_AK    256      // [256]
#define WS_MOM2  520      // [8][4] Seq,Sek,Sek2,Sekq (written by ksv oc==0)
#define WS_SX2B  552      // [8]    batch sum x^2 (written by ksv oc==0)
#define WS_T1P   7424     // [64]
#define WS_T2P   7488     // [64]
#define WS_STAT  20480    // [8] stride 2560: eq, ek, Sv, Sve
#define STAT_STRIDE 2560
#define ST_EQ    0
#define ST_EK    1024
#define ST_SV    2048
#define ST_SVE   2304
// 11 per-channel chunk-partial arrays, each [8][32][256]; arr stride 65536
// 0 sx, 1 xe, 2 xk, 3 vsu, 4 ue, 5 veu, 6 caq, 7 cak, 8 cuak, 9 x2, 10 uu
#define WS_P11   57344    // ends 57344+11*65536 = 778240
#define P11_AS   65536
#define WS_WVB   778240   // [32768] u32: W^T bf16 pairs, swizzled MFMA-B layout

typedef short bf16x8 __attribute__((ext_vector_type(8)));
typedef float f32x4 __attribute__((ext_vector_type(4)));
union FragU { uint4 u; bf16x8 h; };

__device__ __forceinline__ unsigned int bf16lo(float v) {
    unsigned int u = __float_as_uint(v);
    return (u + 0x7FFFu + ((u >> 16) & 1u)) >> 16;
}
__device__ __forceinline__ unsigned int bf16hi(float v) {
    unsigned int u = __float_as_uint(v);
    return (u + 0x7FFFu + ((u >> 16) & 1u)) & 0xFFFF0000u;
}

// kP: blocks 0..255 = (b, n-chunk of 32): owns ALL channels for its n-slice.
// Computes eq/ek/maq/mak fully in-block (writes eq/ek to STAT), then the 11
// per-channel row-dot partials from the SAME LDS tiles — x,u read ONCE
// (kills round-17's kB and its 32MB re-read). Blocks 256..259: Wv pack.
__global__ void kP(const float* __restrict__ x, const float* __restrict__ u,
                   const float* __restrict__ Wq, const float* __restrict__ bq,
                   const float* __restrict__ Wk, const float* __restrict__ bk,
                   const float* __restrict__ Wc, const float* __restrict__ Wv,
                   float* __restrict__ ws) {
    const int bid = blockIdx.x;
    const int t = threadIdx.x;   // 256
    __shared__ float tile_x[256][33];   // 33.8KB (pack path aliases as [64][65])
    __shared__ float tile_u[256][33];
    __shared__ float aql[256], akl[256];
    __shared__ float eq_l[32], ek_l[32], maq_l[32], mak_l[32];
    __shared__ float red4[4][8][32];
    __shared__ float s_cq, s_ck;
    if (bid >= 256) {
        float (*tile)[65] = (float(*)[65])&tile_x[0][0];
        const int o0 = (bid - 256) * 64;
        const int cho = t >> 6, ol = t & 63;
        uint4* wvb4 = (uint4*)((unsigned int*)ws + WS_WVB);
        for (int p4 = 0; p4 < 4; ++p4) {
#pragma unroll 4
            for (int p = 0; p < 16; ++p) {
                int cl = p * 4 + cho;
                tile[cl][ol] = Wv[(size_t)(p4 * 64 + cl) * NC + o0 + ol];
            }
            __syncthreads();
#pragma unroll
            for (int i = 0; i < 2; ++i) {
                int idx2 = i * 256 + t;
                int o_l = idx2 >> 3, gg = idx2 & 7;
                int g = p4 * 8 + gg;
                int o = o0 + o_l;
                int s = g ^ (o & 7);
                uint4 outv;
                outv.x = bf16lo(tile[gg * 8 + 0][o_l]) | bf16hi(tile[gg * 8 + 1][o_l]);
                outv.y = bf16lo(tile[gg * 8 + 2][o_l]) | bf16hi(tile[gg * 8 + 3][o_l]);
                outv.z = bf16lo(tile[gg * 8 + 4][o_l]) | bf16hi(tile[gg * 8 + 5][o_l]);
                outv.w = bf16lo(tile[gg * 8 + 6][o_l]) | bf16hi(tile[gg * 8 + 7][o_l]);
                wvb4[(size_t)(bid - 256) * 2048 + o_l * 32 + s] = outv;
            }
            __syncthreads();
        }
        return;
    }
    const int b = bid >> 5, nc = bid & 31;
    // aq/ak: t = channel (coalesced)
    {
        float a = 0.f, k = 0.f;
#pragma unroll 8
        for (int o = 0; o < 64; ++o) {
            a += Wc[o] * Wq[o * NC + t];
            k += Wc[64 + o] * Wk[o * NC + t];
        }
        aql[t] = a; akl[t] = k;
        if (nc == 0) { ws[WS_AQ + t] = a; ws[WS_AK + t] = k; }
    }
    if (t < 64) {
        float p = Wc[t] * bq[t], rr = Wc[64 + t] * bk[t];
        for (int off = 32; off > 0; off >>= 1) {
            p += __shfl_down(p, off, 64);
            rr += __shfl_down(rr, off, 64);
        }
        if (t == 0) { s_cq = p; s_ck = rr; }
    }
    // load tiles (coalesced 128B segments)
    const float* xb = x + (size_t)b * NC * NN + nc * 32;
    const float* ub = u + (size_t)b * NC * NN + nc * 32;
    {
        const int cs = t >> 5, nl = t & 31;
#pragma unroll 8
        for (int r2 = 0; r2 < 32; ++r2) {
            int c = r2 * 8 + cs;
            tile_x[c][nl] = xb[(size_t)c * NN + nl];
            tile_u[c][nl] = ub[(size_t)c * NN + nl];
        }
    }
    __syncthreads();
    // eq/ek/maq/mak: nl = t&31, grp = t>>5 sums its 32-channel slice
    {
        const int nl = t & 31, grp = t >> 5;
        float ea = 0.f, ka = 0.f, ma = 0.f, mk = 0.f;
#pragma unroll 8
        for (int i = 0; i < 32; ++i) {
            int c = grp * 32 + i;
            float xv = tile_x[c][nl], uv = tile_u[c][nl];
            float a = aql[c], kk = akl[c];
            ea += a * xv; ka += kk * xv;
            ma += a * uv; mk += kk * uv;
        }
        red4[0][grp][nl] = ea; red4[1][grp][nl] = ka;
        red4[2][grp][nl] = ma; red4[3][grp][nl] = mk;
    }
    __syncthreads();
    if (t < 32) {
        float e = 0.f, k = 0.f, m = 0.f, mq = 0.f;
#pragma unroll
        for (int g = 0; g < 8; ++g) {
            e += red4[0][g][t]; k += red4[1][g][t];
            m += red4[2][g][t]; mq += red4[3][g][t];
        }
        e += s_cq; k += s_ck;
        eq_l[t] = e; ek_l[t] = k; maq_l[t] = m; mak_l[t] = mq;
        float* st = ws + WS_STAT + b * STAT_STRIDE;
        st[ST_EQ + nc * 32 + t] = e;
        st[ST_EK + nc * 32 + t] = k;
    }
    __syncthreads();
    // row-dots from LDS tiles: t = channel
    {
        float acc[11];
#pragma unroll
        for (int a2 = 0; a2 < 11; ++a2) acc[a2] = 0.f;
#pragma unroll 8
        for (int n = 0; n < 32; ++n) {
            float xv = tile_x[t][n], uv = tile_u[t][n];
            float e = eq_l[n], kk = ek_l[n], m = maq_l[n], mq = mak_l[n];
            acc[0] += xv;        // sx
            acc[1] += xv * e;    // xe
            acc[2] += xv * kk;   // xk
            acc[3] += uv;        // vsu
            acc[4] += uv * e;    // ue
            acc[5] += uv * kk;   // veu
            acc[6] += xv * m;    // caq
            acc[7] += xv * mq;   // cak
            acc[8] += uv * mq;   // cuak
            acc[9] += xv * xv;   // x2
            acc[10] += uv * uv;  // uu
        }
        const int idx = (b * 32 + nc) * 256 + t;
#pragma unroll
        for (int a2 = 0; a2 < 11; ++a2)
            ws[WS_P11 + a2 * P11_AS + idx] = acc[a2];
    }
}

// ksv: 64 blocks (b, oc). Moments from STAT eq/ek; reduce sx/xe/xk partials
// (redundant per block, L2-resident); Sv/Sve matvec + T1/T2; oc==0 also
// writes MOM2 and SX2B.
__global__ void ksv(const float* __restrict__ Wv, const float* __restrict__ bv,
                    const float* __restrict__ Wc, const float* __restrict__ bq,
                    const float* __restrict__ bk, float* __restrict__ ws) {
    const int bid = blockIdx.x;          // 64: b*8 + oc
    const int b = bid >> 3, oc = bid & 7;
    const int t = threadIdx.x;           // 256
    const int wid = t >> 6, lane = t & 63;
    const int o_sub = t >> 3, ks = t & 7;
    const int o = oc * 32 + o_sub;
    __shared__ float sxl[NC], xel[NC], xkl[NC];
    __shared__ float T1s[32], T2s[32];
    __shared__ float mred[5][4];
    __shared__ float s_cq, s_ck;
    if (t < 64) {
        float p = Wc[t] * bq[t], rr = Wc[64 + t] * bk[t];
        for (int off = 32; off > 0; off >>= 1) {
            p += __shfl_down(p, off, 64);
            rr += __shfl_down(rr, off, 64);
        }
        if (t == 0) { s_cq = p; s_ck = rr; }
    }
    // per-channel reduces (32 chunks), coalesced
    {
        float sxa = 0.f, xea = 0.f, xka = 0.f, x2a = 0.f;
#pragma unroll 8
        for (int ncc = 0; ncc < 32; ++ncc) {
            const int idx = (b * 32 + ncc) * 256 + t;
            sxa += ws[WS_P11 + 0 * P11_AS + idx];
            xea += ws[WS_P11 + 1 * P11_AS + idx];
            xka += ws[WS_P11 + 2 * P11_AS + idx];
            if (oc == 0) x2a += ws[WS_P11 + 9 * P11_AS + idx];
        }
        sxl[t] = sxa; xel[t] = xea; xkl[t] = xka;
        if (oc == 0) {
            for (int off = 32; off > 0; off >>= 1) x2a += __shfl_down(x2a, off, 64);
            if (lane == 0) mred[4][wid] = x2a;
        }
    }
    // moments from STAT eq/ek
    {
        const float* st = ws + WS_STAT + b * STAT_STRIDE;
        float4 e4 = ((const float4*)(st + ST_EQ))[t];
        float4 k4 = ((const float4*)(st + ST_EK))[t];
        float d0 = e4.x + e4.y + e4.z + e4.w;
        float d1 = k4.x + k4.y + k4.z + k4.w;
        float d2 = k4.x * k4.x + k4.y * k4.y + k4.z * k4.z + k4.w * k4.w;
        float d3 = e4.x * k4.x + e4.y * k4.y + e4.z * k4.z + e4.w * k4.w;
        for (int off = 32; off > 0; off >>= 1) {
            d0 += __shfl_down(d0, off, 64);
            d1 += __shfl_down(d1, off, 64);
            d2 += __shfl_down(d2, off, 64);
            d3 += __shfl_down(d3, off, 64);
        }
        if (lane == 0) { mred[0][wid] = d0; mred[1][wid] = d1; mred[2][wid] = d2; mred[3][wid] = d3; }
    }
    __syncthreads();
    const float Seq  = mred[0][0] + mred[0][1] + mred[0][2] + mred[0][3];
    const float Sek  = mred[1][0] + mred[1][1] + mred[1][2] + mred[1][3];
    const float Sek2 = mred[2][0] + mred[2][1] + mred[2][2] + mred[2][3];
    const float Sekq = mred[3][0] + mred[3][1] + mred[3][2] + mred[3][3];
    if (oc == 0 && t == 0) {
        ws[WS_MOM2 + b * 4 + 0] = Seq;
        ws[WS_MOM2 + b * 4 + 1] = Sek;
        ws[WS_MOM2 + b * 4 + 2] = Sek2;
        ws[WS_MOM2 + b * 4 + 3] = Sekq;
        ws[WS_SX2B + b] = mred[4][0] + mred[4][1] + mred[4][2] + mred[4][3];
    }
    const float cq = s_cq, ck = s_ck;
    float wsx = 0.f, wxe = 0.f;
    const float4* wrow = (const float4*)(Wv + (size_t)o * NC);
#pragma unroll
    for (int i = 0; i < 8; ++i) {
        float4 w4 = wrow[i * 8 + ks];
        int k = i * 32 + ks * 4;
        wsx += w4.x * sxl[k] + w4.y * sxl[k + 1] + w4.z * sxl[k + 2] + w4.w * sxl[k + 3];
        wxe += w4.x * xel[k] + w4.y * xel[k + 1] + w4.z * xel[k + 2] + w4.w * xel[k + 3];
    }
    for (int off = 4; off > 0; off >>= 1) {
        wsx += __shfl_down(wsx, off, 8);
        wxe += __shfl_down(wxe, off, 8);
    }
    if (ks == 0) {
        float bvc = bv[o];
        float Sv  = wsx + (float)NN * bvc;
        float SvL = wsx;
        float Sve = wxe + bvc * Seq;
        float* st = ws + WS_STAT + b * STAT_STRIDE;
        st[ST_SV + o] = Sv; st[ST_SVE + o] = Sve;
        float A = 2.f * Sve - bvc * Seq - cq * Sv;
        float sx = sxl[o];
        float xk = xkl[o];
        float xkL = xk - ck * sx;
        float T1c = A * sx + Sv * xkL + SvL * xk;
        float SP  = Sek - (float)NN * ck;
        float SP2 = Sek2 - 2.f * ck * Sek + (float)NN * ck * ck;
        float SPQ = Sek2 - ck * Sek;
        float T2c = (float)NN * A * A + Sv * Sv * SP2 + SvL * SvL * Sek2
                  + 2.f * A * Sv * SP + 2.f * A * SvL * Sek + 2.f * Sv * SvL * SPQ;
        T1s[o_sub] = T1c; T2s[o_sub] = T2c;
    }
    __syncthreads();
    if (t == 0) {
        float t1 = 0.f, t2 = 0.f;
        for (int i = 0; i < 32; ++i) { t1 += T1s[i]; t2 += T2s[i]; }
        ws[WS_T1P + bid] = t1;
        ws[WS_T2P + bid] = t2;
    }
}

// kfin: blocks 0..7 = MFMA recursion (r15/r17 verified); 8..519 = output-0.
// Recursion prologue reduces its batch's 8 per-channel arrays from P11,
// using the not-yet-written Wlds region as scratch.
struct KFSMem {
    unsigned int Wlds[32768];               // 128KB W^T bf16, swizzled
    unsigned int Vsb[128] __attribute__((aligned(16)));
    unsigned int Veb[128] __attribute__((aligned(16)));
    float P_lds[256];
    float R_lds[256];
    float dred[9][4];
    float redu[16];
    float sge;
};

__global__ void __launch_bounds__(1024, 4) kfin(
        const float* __restrict__ x, const float* __restrict__ bv,
        const float* __restrict__ gamma, float* __restrict__ ws,
        float* __restrict__ out) {
    __shared__ __align__(16) unsigned char smem_raw[sizeof(KFSMem)];
    KFSMem& S = *(KFSMem*)smem_raw;
    const int bid = blockIdx.x;      // 520
    const int t = threadIdx.x;       // 1024
    const int lane = t & 63;
    const bool is_iter = (bid < 8);
    uint4 stg0, stg1, stg2, stg3, stg4, stg5, stg6, stg7;
    if (is_iter) {
        const uint4* wvb4 = (const uint4*)((const unsigned int*)ws + WS_WVB);
        stg0 = wvb4[0 * 1024 + t]; stg1 = wvb4[1 * 1024 + t];
        stg2 = wvb4[2 * 1024 + t]; stg3 = wvb4[3 * 1024 + t];
        stg4 = wvb4[4 * 1024 + t]; stg5 = wvb4[5 * 1024 + t];
        stg6 = wvb4[6 * 1024 + t]; stg7 = wvb4[7 * 1024 + t];
    }
    // gamma_eff: SX2B[8] + T1P[64] + T2P[64] (all wave 0)
    {
        float a = 0.f, b1 = 0.f, c1 = 0.f;
        if (t < 8) a = ws[WS_SX2B + t];
        if (t < 64) { b1 = ws[WS_T1P + t]; c1 = ws[WS_T2P + t]; }
        for (int off = 32; off > 0; off >>= 1) {
            a  += __shfl_down(a,  off, 64);
            b1 += __shfl_down(b1, off, 64);
            c1 += __shfl_down(c1, off, 64);
        }
        if (t == 0) {
            float inv = gamma[0] * (1.f / (float)NN);
            float dd = a + 2.f * inv * b1 + inv * inv * c1;
            float lip = sqrtf(dd / a);
            S.sge = gamma[0] * ((lip > 0.9f) ? (0.9f / lip) : 1.f);
        }
    }
    __syncthreads();
    const float ge = S.sge;

    if (!is_iter) {
        const float gn = ge * (1.f / (float)NN);
        const int r = t >> 8, tc = t & 255;
        const int bid2 = (bid - 8) * 4 + r;
        const int b = bid2 >> 8, c = bid2 & 255;
        const float* st = ws + WS_STAT + b * STAT_STRIDE;
        float sv = st[ST_SV + c], sve = st[ST_SVE + c];
        float4 ek4 = ((const float4*)(st + ST_EK))[tc];
        size_t i4 = (size_t)bid2 * 256 + tc;
        float4 x4 = ((const float4*)x)[i4];
        float4 o;
        o.x = 2.f * x4.x + gn * (sve + ek4.x * sv);
        o.y = 2.f * x4.y + gn * (sve + ek4.y * sv);
        o.z = 2.f * x4.z + gn * (sve + ek4.z * sv);
        o.w = 2.f * x4.w + gn * (sve + ek4.w * sv);
        ((float4*)out)[i4] = o;
        return;
    }

    // ---------------- recursion blocks ----------------
    const int b = bid;
    const int nt = t >> 6;
    const int row = lane & 15;
    const int kgrp = lane >> 4;
    const int o = nt * 16 + row;
    const int wid4 = (t & 255) >> 6;
    // per-channel P11 reduce using Wlds region as scratch (before Wlds write)
    float* redq = (float*)S.Wlds;    // [4][8*256]
    {
        const int c = t & 255, q = t >> 8;
        float r8[8];
#pragma unroll
        for (int a2 = 0; a2 < 8; ++a2) r8[a2] = 0.f;
        float uup = 0.f;
#pragma unroll
        for (int n2 = 0; n2 < 8; ++n2) {
            const int idx = (b * 32 + q * 8 + n2) * 256 + c;
            r8[0] += ws[WS_P11 + 0 * P11_AS + idx];   // sx
            r8[1] += ws[WS_P11 + 2 * P11_AS + idx];   // xk
            r8[2] += ws[WS_P11 + 3 * P11_AS + idx];   // vsu
            r8[3] += ws[WS_P11 + 4 * P11_AS + idx];   // ue
            r8[4] += ws[WS_P11 + 5 * P11_AS + idx];   // veu
            r8[5] += ws[WS_P11 + 6 * P11_AS + idx];   // caq
            r8[6] += ws[WS_P11 + 7 * P11_AS + idx];   // cak
            r8[7] += ws[WS_P11 + 8 * P11_AS + idx];   // cuak
            uup   += ws[WS_P11 + 10 * P11_AS + idx];  // uu
        }
#pragma unroll
        for (int a2 = 0; a2 < 8; ++a2) redq[q * 2048 + a2 * 256 + c] = r8[a2];
        for (int off = 32; off > 0; off >>= 1) uup += __shfl_down(uup, off, 64);
        if (lane == 0) S.redu[t >> 6] = uup;
    }
    __syncthreads();
    const float s = ge * (1.f / (float)NN);
    float Svl_r = 0.f, sxl_r = 0.f, xkl_r = 0.f, caql_r = 0.f, cakl_r = 0.f,
          Uel_r = 0.f, Vsul_r = 0.f, bvl_r = 0.f, aql_r = 0.f, akl_r = 0.f,
          veu_r = 0.f, cuak_r = 0.f, vsreg = 0.f, vereg = 0.f;
    float uu = 0.f;
    if (t < 256) {
        float f[8];
#pragma unroll
        for (int a2 = 0; a2 < 8; ++a2)
            f[a2] = redq[0 * 2048 + a2 * 256 + t] + redq[1 * 2048 + a2 * 256 + t]
                  + redq[2 * 2048 + a2 * 256 + t] + redq[3 * 2048 + a2 * 256 + t];
        sxl_r = f[0]; xkl_r = f[1]; Vsul_r = f[2]; Uel_r = f[3];
        veu_r = f[4]; caql_r = f[5]; cakl_r = f[6]; cuak_r = f[7];
        const float* st = ws + WS_STAT + b * STAT_STRIDE;
        Svl_r = st[ST_SV + t];
        aql_r = ws[WS_AQ + t];
        akl_r = ws[WS_AK + t];
        bvl_r = bv[t];
        vsreg = Vsul_r; vereg = veu_r;
        for (int g = 0; g < 16; ++g) uu += S.redu[g];
        float vs_o = __shfl_xor(vsreg, 1, 64);
        float ve_o = __shfl_xor(vereg, 1, 64);
        if ((t & 1) == 0) {
            S.Vsb[t >> 1] = bf16lo(vsreg) | bf16hi(vs_o);
            S.Veb[t >> 1] = bf16lo(vereg) | bf16hi(ve_o);
        }
    }
    const float Seq  = ws[WS_MOM2 + b * 4 + 0];
    const float Sek  = ws[WS_MOM2 + b * 4 + 1];
    const float Sekq = ws[WS_MOM2 + b * 4 + 3];
    __syncthreads();   // all reads of redq done
    // write staged W to LDS (overwrites redq scratch)
    ((uint4*)S.Wlds)[0 * 1024 + t] = stg0; ((uint4*)S.Wlds)[1 * 1024 + t] = stg1;
    ((uint4*)S.Wlds)[2 * 1024 + t] = stg2; ((uint4*)S.Wlds)[3 * 1024 + t] = stg3;
    ((uint4*)S.Wlds)[4 * 1024 + t] = stg4; ((uint4*)S.Wlds)[5 * 1024 + t] = stg5;
    ((uint4*)S.Wlds)[6 * 1024 + t] = stg6; ((uint4*)S.Wlds)[7 * 1024 + t] = stg7;
    // prologue dots
    if (t < 256) {
        float d[8] = {Svl_r * cuak_r, aql_r * Vsul_r, akl_r * Vsul_r, akl_r * Uel_r,
                      Svl_r * Vsul_r, Svl_r * veu_r,  Svl_r * aql_r,  Svl_r * akl_r};
        for (int off = 32; off > 0; off >>= 1)
            for (int m = 0; m < 8; ++m) d[m] += __shfl_down(d[m], off, 64);
        if (lane == 0) for (int m = 0; m < 8; ++m) S.dred[m][wid4] = d[m];
    }
    __syncthreads();
    float g2a = 0.f, aqVsu = 0.f, akVsu = 0.f, akUe = 0.f, SvVsu = 0.f, SvVeu = 0.f,
          Svaq = 0.f, Svak = 0.f;
    if (t < 256) {
        g2a   = S.dred[0][0] + S.dred[0][1] + S.dred[0][2] + S.dred[0][3];
        aqVsu = S.dred[1][0] + S.dred[1][1] + S.dred[1][2] + S.dred[1][3];
        akVsu = S.dred[2][0] + S.dred[2][1] + S.dred[2][2] + S.dred[2][3];
        akUe  = S.dred[3][0] + S.dred[3][1] + S.dred[3][2] + S.dred[3][3];
        SvVsu = S.dred[4][0] + S.dred[4][1] + S.dred[4][2] + S.dred[4][3];
        SvVeu = S.dred[5][0] + S.dred[5][1] + S.dred[5][2] + S.dred[5][3];
        Svaq  = S.dred[6][0] + S.dred[6][1] + S.dred[6][2] + S.dred[6][3];
        Svak  = S.dred[7][0] + S.dred[7][1] + S.dred[7][2] + S.dred[7][3];
    }
    __syncthreads();
    const float lam = 1.f + s * Svak;
    float alpha = 1.f, beta = 0.f, gam = 0.f;
    float SxAcc = 0.f, XkAcc = 0.f, CakAcc = 0.f;
    float dot = uu, tr = 0.f;
    const float coef[5] = {1.f, -0.5f, 1.f / 3.f, -0.25f, 0.2f};
    const uint4* Vsb4 = (const uint4*)S.Vsb;
    const uint4* Veb4 = (const uint4*)S.Veb;
    const uint4* Wlds4 = (const uint4*)S.Wlds;
    for (int j = 0; j < 5; ++j) {
        f32x4 acc = {0.f, 0.f, 0.f, 0.f};
#pragma unroll
        for (int kc = 0; kc < 8; ++kc) {
            const uint4* asrc = (row == 1) ? Veb4 : Vsb4;
            uint4 araw = asrc[kc * 4 + kgrp];
            if (row >= 2) { araw.x = 0u; araw.y = 0u; araw.z = 0u; araw.w = 0u; }
            FragU fa; fa.u = araw;
            FragU fb; fb.u = Wlds4[o * 32 + ((kc * 4 + kgrp) ^ (o & 7))];
            acc = __builtin_amdgcn_mfma_f32_16x16x32_bf16(fa.h, fb.h, acc, 0, 0, 0);
        }
        if (lane < 16) {
            S.P_lds[nt * 16 + lane] = acc[0];
            S.R_lds[nt * 16 + lane] = acc[1];
        }
        __syncthreads();
        if (t < 256) {
            float Pv = s * S.P_lds[t];
            float Rv = s * S.R_lds[t];
            float d[9];
            d[0] = Svl_r * Pv;
            d[1] = Svl_r * Rv;
            d[2] = bvl_r * vsreg;
            d[3] = sxl_r * Pv;
            d[4] = xkl_r * Pv;
            d[5] = caql_r * Pv;
            d[6] = cakl_r * Pv;
            d[7] = Uel_r * Pv;
            d[8] = Vsul_r * Rv;
            for (int off = 32; off > 0; off >>= 1)
                for (int m = 0; m < 9; ++m) d[m] += __shfl_down(d[m], off, 64);
            if (lane == 0) for (int m = 0; m < 9; ++m) S.dred[m][wid4] = d[m];
        }
        __syncthreads();
        if (t < 256) {
            float Pv = s * S.P_lds[t];
            float Rv = s * S.R_lds[t];
            float sm[9];
            for (int m = 0; m < 9; ++m)
                sm[m] = S.dred[m][0] + S.dred[m][1] + S.dred[m][2] + S.dred[m][3];
            const float svP = sm[0], svR = sm[1], bvVs = sm[2], sxP = sm[3], xkP = sm[4],
                        caqP = sm[5], cakP = sm[6], ueP = sm[7], vsuR = sm[8];
            const float sB = s * bvVs;
            float St  = s * (alpha * SvVsu + beta * (float)NN + gam * Seq  + Svaq * SxAcc);
            float tek = s * (alpha * SvVeu + beta * Sek        + gam * Sekq + Svaq * XkAcc);
            float uta = s * (alpha * g2a   + beta * akVsu      + gam * akUe + Svaq * CakAcc);
            dot += ueP + caqP + sB * aqVsu + uta + vsuR;
            tr  += coef[j] * dot;
            float nVs = vsreg + Pv * Seq  + aql_r * (sxP + (float)NN * sB) + akl_r * St  + Rv * (float)NN;
            float nVe = vereg + Pv * Sekq + aql_r * (xkP + sB * Sek)       + akl_r * tek + Rv * Sek;
            vsreg = nVs; vereg = nVe;
            float vs_o = __shfl_xor(nVs, 1, 64);
            float ve_o = __shfl_xor(nVe, 1, 64);
            if ((t & 1) == 0) {
                S.Vsb[t >> 1] = bf16lo(nVs) | bf16hi(vs_o);
                S.Veb[t >> 1] = bf16lo(nVe) | bf16hi(ve_o);
            }
            SxAcc  = lam * SxAcc  + sxP;
            XkAcc  = lam * XkAcc  + xkP;
            CakAcc = lam * CakAcc + cakP;
            beta = lam * beta + Svaq * sB + svR;
            gam  = lam * gam + svP;
            alpha *= lam;
        }
        __syncthreads();
    }
    if (t == 0) out[2097152 + b] = tr;
}

extern "C" void kernel_launch(void* const* d_in, const int* in_sizes, int n_in,
                              void* d_out, int out_size, void* d_ws, size_t ws_size,
                              hipStream_t stream) {
    const float* x     = (const float*)d_in[0];
    const float* Wq    = (const float*)d_in[1];
    const float* bq    = (const float*)d_in[2];
    const float* Wk    = (const float*)d_in[3];
    const float* bk    = (const float*)d_in[4];
    const float* Wc    = (const float*)d_in[5];
    const float* Wv    = (const float*)d_in[6];
    const float* bv    = (const float*)d_in[7];
    const float* gamma = (const float*)d_in[8];
    const float* u     = (const float*)d_in[9];
    float* out = (float*)d_out;
    float* ws  = (float*)d_ws;

    kP  <<<dim3(260), dim3(256),  0, stream>>>(x, u, Wq, bq, Wk, bk, Wc, Wv, ws);
    ksv <<<dim3(64),  dim3(256),  0, stream>>>(Wv, bv, Wc, bq, bk, ws);
    kfin<<<dim3(520), dim3(1024), 0, stream>>>(x, bv, gamma, ws, out);
}

// Round 19
// 45.206 us; speedup vs baseline: 1.1880x; 1.1880x over previous
//
#include <hip/hip_runtime.h>
#include <math.h>

// Problem constants
#define NB 8      // batch
#define NC 256    // channels
#define NN 1024   // spatial H*W
#define NICH 64   // inter channels

// ws layout (float offsets)
#define WS_AQ    0        // [256]
#define WS_AK    256      // [256]
#define WS_MOM2  520      // [8][4]: Seq,Sek,Sek2,Sekq per batch
#define WS_SX    1024     // [8][256]
#define WS_XE    3072     // [8][256]
#define WS_XK    5120     // [8][256]
#define WS_T1P   7424     // [64]
#define WS_T2P   7488     // [64]
#define WS_VSU   7680     // [8][256]
#define WS_UE    9728     // [8][256]
#define WS_VEU   11776    // [8][256]
#define WS_CAQ   13824    // [8][256]
#define WS_CAK   15872    // [8][256]
#define WS_CUAK  17920    // [8][256]
#define WS_STAT  20480    // [8] stride 2560: (ek, Sv, Sve used)
#define STAT_STRIDE 2560
#define ST_EK    1024
#define ST_SV    2048
#define ST_SVE   2304
#define WS_EQP2  57344    // [32][1024] depth-4 partials (b*4+chq)
#define WS_EKP2  90112    // [32][1024]
#define WS_MAQP2 122880   // [32][1024]
#define WS_MAKP2 155648   // [32][1024] ends 188416
#define WS_SX2P  188416   // [256]
#define WS_UUP   188672   // [256]
#define WS_WVB   188928   // [32768] u32: W^T bf16 pairs, swizzled MFMA-B layout

typedef short bf16x8 __attribute__((ext_vector_type(8)));
typedef float f32x4 __attribute__((ext_vector_type(4)));
union FragU { uint4 u; bf16x8 h; };

__device__ __forceinline__ float dot4(const float4& a, const float4& b) {
    return a.x * b.x + a.y * b.y + a.z * b.z + a.w * b.w;
}
__device__ __forceinline__ float sum4(const float4& a) {
    return a.x + a.y + a.z + a.w;
}
__device__ __forceinline__ unsigned int bf16lo(float v) {
    unsigned int u = __float_as_uint(v);
    return (u + 0x7FFFu + ((u >> 16) & 1u)) >> 16;
}
__device__ __forceinline__ unsigned int bf16hi(float v) {
    unsigned int u = __float_as_uint(v);
    return (u + 0x7FFFu + ((u >> 16) & 1u)) & 0xFFFF0000u;
}

// kA: depth-4 partials of eq/ek/maq/mak (blocks 0..255; float4 loads) + W^T
// bf16 MFMA-B conversion (blocks 256..259). Pack tile [64][65] in 4 passes:
// kA static LDS 33KB -> 4 blocks/CU for the 256 streaming blocks.
__global__ void kA(const float* __restrict__ x, const float* __restrict__ u,
                   const float* __restrict__ Wq, const float* __restrict__ Wk,
                   const float* __restrict__ Wc, const float* __restrict__ Wv,
                   float* __restrict__ ws) {
    const int bid = blockIdx.x;
    const int t = threadIdx.x;   // 256
    __shared__ float tile[64][65];   // 16.6KB transpose tile (4 passes)
    __shared__ float aql[64], akl[64];
    __shared__ float4 red_e[32][8], red_k[32][8], red_a[32][8], red_m[32][8];
    if (bid >= 256) {
        const int o0 = (bid - 256) * 64;
        const int cho = t >> 6, ol = t & 63;
        uint4* wvb4 = (uint4*)((unsigned int*)ws + WS_WVB);
        for (int p4 = 0; p4 < 4; ++p4) {
#pragma unroll 4
            for (int p = 0; p < 16; ++p) {
                int cl = p * 4 + cho;
                tile[cl][ol] = Wv[(size_t)(p4 * 64 + cl) * NC + o0 + ol];
            }
            __syncthreads();
#pragma unroll
            for (int i = 0; i < 2; ++i) {
                int idx2 = i * 256 + t;
                int o_l = idx2 >> 3, gg = idx2 & 7;
                int g = p4 * 8 + gg;
                int o = o0 + o_l;
                int s = g ^ (o & 7);
                uint4 outv;
                outv.x = bf16lo(tile[gg * 8 + 0][o_l]) | bf16hi(tile[gg * 8 + 1][o_l]);
                outv.y = bf16lo(tile[gg * 8 + 2][o_l]) | bf16hi(tile[gg * 8 + 3][o_l]);
                outv.z = bf16lo(tile[gg * 8 + 4][o_l]) | bf16hi(tile[gg * 8 + 5][o_l]);
                outv.w = bf16lo(tile[gg * 8 + 6][o_l]) | bf16hi(tile[gg * 8 + 7][o_l]);
                wvb4[(size_t)(bid - 256) * 2048 + o_l * 32 + s] = outv;
            }
            __syncthreads();
        }
        return;
    }
    const int b = bid >> 5, r = bid & 31;
    const int nq = r >> 2, chq = r & 3;
    // aq/ak for this 64-channel quarter — lane = channel (coalesced 256B loads)
    if (t < 64) {
        const int c = chq * 64 + t;
        float a = 0.f, k = 0.f;
#pragma unroll 8
        for (int o = 0; o < 64; ++o) {
            a += Wc[o] * Wq[o * NC + c];
            k += Wc[64 + o] * Wk[o * NC + c];
        }
        aql[t] = a; akl[t] = k;
        if (nq == 0) { ws[WS_AQ + c] = a; ws[WS_AK + c] = k; }
    }
    __syncthreads();
    const int f4g = t & 31, sub = t >> 5;   // 32 float4-groups x 8 ch-subsets
    const float4* xb4 = (const float4*)(x + ((size_t)b * NC + chq * 64) * NN);
    const float4* ub4 = (const float4*)(u + ((size_t)b * NC + chq * 64) * NN);
    float4 eqp = {0.f, 0.f, 0.f, 0.f}, ekp = {0.f, 0.f, 0.f, 0.f};
    float4 map = {0.f, 0.f, 0.f, 0.f}, mkp = {0.f, 0.f, 0.f, 0.f};
#pragma unroll
    for (int i = 0; i < 8; ++i) {
        const int cl = sub * 8 + i;
        float4 xv = xb4[cl * 256 + nq * 32 + f4g];
        float4 uv = ub4[cl * 256 + nq * 32 + f4g];
        const float a = aql[cl], kk = akl[cl];
        eqp.x += a * xv.x;  eqp.y += a * xv.y;  eqp.z += a * xv.z;  eqp.w += a * xv.w;
        ekp.x += kk * xv.x; ekp.y += kk * xv.y; ekp.z += kk * xv.z; ekp.w += kk * xv.w;
        map.x += a * uv.x;  map.y += a * uv.y;  map.z += a * uv.z;  map.w += a * uv.w;
        mkp.x += kk * uv.x; mkp.y += kk * uv.y; mkp.z += kk * uv.z; mkp.w += kk * uv.w;
    }
    red_e[f4g][sub] = eqp; red_k[f4g][sub] = ekp;
    red_a[f4g][sub] = map; red_m[f4g][sub] = mkp;
    __syncthreads();
    if (t < 32) {
        float4 e = red_e[t][0], k = red_k[t][0], a = red_a[t][0], m = red_m[t][0];
#pragma unroll
        for (int s2 = 1; s2 < 8; ++s2) {
            float4 v;
            v = red_e[t][s2]; e.x += v.x; e.y += v.y; e.z += v.z; e.w += v.w;
            v = red_k[t][s2]; k.x += v.x; k.y += v.y; k.z += v.z; k.w += v.w;
            v = red_a[t][s2]; a.x += v.x; a.y += v.y; a.z += v.z; a.w += v.w;
            v = red_m[t][s2]; m.x += v.x; m.y += v.y; m.z += v.z; m.w += v.w;
        }
        const size_t po = (size_t)(b * 4 + chq) * 1024 + nq * 128;
        ((float4*)(ws + WS_EQP2  + po))[t] = e;
        ((float4*)(ws + WS_EKP2  + po))[t] = k;
        ((float4*)(ws + WS_MAQP2 + po))[t] = a;
        ((float4*)(ws + WS_MAKP2 + po))[t] = m;
    }
}

// kB: finalize eq/ek/maq/mak (4 partials in-register), moments, row-dots.
__global__ void kB(const float* __restrict__ x, const float* __restrict__ u,
                   const float* __restrict__ Wc, const float* __restrict__ bq,
                   const float* __restrict__ bk, float* __restrict__ ws) {
    const int bid = blockIdx.x;
    const int b = bid >> 5, g = bid & 31;
    const int c0 = g * 8;
    const int t = threadIdx.x;   // 256
    const int wid = t >> 6, lane = t & 63;
    __shared__ float s_cq, s_ck;
    __shared__ float mred[4][4];
    __shared__ float wv9[8][9][4];
    __shared__ float accw[2][4];
    if (t < 64) {
        float p = Wc[t] * bq[t], rr = Wc[64 + t] * bk[t];
        for (int off = 32; off > 0; off >>= 1) {
            p += __shfl_down(p, off, 64);
            rr += __shfl_down(rr, off, 64);
        }
        if (t == 0) { s_cq = p; s_ck = rr; }
    }
    __syncthreads();
    const float cq = s_cq, ck = s_ck;
    float4 e4 = {0.f, 0.f, 0.f, 0.f}, k4 = {0.f, 0.f, 0.f, 0.f};
    float4 ma4 = {0.f, 0.f, 0.f, 0.f}, mk4 = {0.f, 0.f, 0.f, 0.f};
#pragma unroll
    for (int q = 0; q < 4; ++q) {
        const size_t po = (size_t)(b * 4 + q) * 1024;
        float4 v;
        v = ((const float4*)(ws + WS_EQP2  + po))[t];
        e4.x += v.x; e4.y += v.y; e4.z += v.z; e4.w += v.w;
        v = ((const float4*)(ws + WS_EKP2  + po))[t];
        k4.x += v.x; k4.y += v.y; k4.z += v.z; k4.w += v.w;
        v = ((const float4*)(ws + WS_MAQP2 + po))[t];
        ma4.x += v.x; ma4.y += v.y; ma4.z += v.z; ma4.w += v.w;
        v = ((const float4*)(ws + WS_MAKP2 + po))[t];
        mk4.x += v.x; mk4.y += v.y; mk4.z += v.z; mk4.w += v.w;
    }
    e4.x += cq; e4.y += cq; e4.z += cq; e4.w += cq;
    k4.x += ck; k4.y += ck; k4.z += ck; k4.w += ck;
    {
        float d0 = sum4(e4), d1 = sum4(k4), d2 = dot4(k4, k4), d3 = dot4(e4, k4);
        for (int off = 32; off > 0; off >>= 1) {
            d0 += __shfl_down(d0, off, 64);
            d1 += __shfl_down(d1, off, 64);
            d2 += __shfl_down(d2, off, 64);
            d3 += __shfl_down(d3, off, 64);
        }
        if (lane == 0) { mred[0][wid] = d0; mred[1][wid] = d1; mred[2][wid] = d2; mred[3][wid] = d3; }
    }
    __syncthreads();
    if (t == 0)
        for (int m = 0; m < 4; ++m)
            ws[WS_MOM2 + b * 4 + m] = mred[m][0] + mred[m][1] + mred[m][2] + mred[m][3];
    if (g == 0)
        ((float4*)(ws + WS_STAT + b * STAT_STRIDE + ST_EK))[t] = k4;
    const float4* xb4 = (const float4*)(x + ((size_t)b * NC + c0) * NN);
    const float4* ub4 = (const float4*)(u + ((size_t)b * NC + c0) * NN);
    float x2a = 0.f, uua = 0.f;
#pragma unroll
    for (int c = 0; c < 8; ++c) {
        float4 xv = xb4[c * 256 + t];
        float4 uv = ub4[c * 256 + t];
        float d[9];
        d[0] = dot4(xv, e4);   // xe
        d[1] = dot4(xv, k4);   // xk
        d[2] = sum4(uv);       // Vsu
        d[3] = dot4(uv, e4);   // Ue
        d[4] = dot4(uv, k4);   // Veu
        d[5] = dot4(xv, ma4);  // caq
        d[6] = dot4(xv, mk4);  // cak
        d[7] = dot4(uv, mk4);  // cuak
        d[8] = sum4(xv);       // sx
        x2a += dot4(xv, xv);
        uua += dot4(uv, uv);
        for (int off = 32; off > 0; off >>= 1)
            for (int m = 0; m < 9; ++m) d[m] += __shfl_down(d[m], off, 64);
        if (lane == 0) for (int m = 0; m < 9; ++m) wv9[c][m][wid] = d[m];
    }
    for (int off = 32; off > 0; off >>= 1) {
        x2a += __shfl_down(x2a, off, 64);
        uua += __shfl_down(uua, off, 64);
    }
    if (lane == 0) { accw[0][wid] = x2a; accw[1][wid] = uua; }
    __syncthreads();
    if (t < 8) {
        int c = t;
        float v[9];
        for (int m = 0; m < 9; ++m)
            v[m] = wv9[c][m][0] + wv9[c][m][1] + wv9[c][m][2] + wv9[c][m][3];
        ws[WS_XE   + b * NC + c0 + c] = v[0];
        ws[WS_XK   + b * NC + c0 + c] = v[1];
        ws[WS_VSU  + b * NC + c0 + c] = v[2];
        ws[WS_UE   + b * NC + c0 + c] = v[3];
        ws[WS_VEU  + b * NC + c0 + c] = v[4];
        ws[WS_CAQ  + b * NC + c0 + c] = v[5];
        ws[WS_CAK  + b * NC + c0 + c] = v[6];
        ws[WS_CUAK + b * NC + c0 + c] = v[7];
        ws[WS_SX   + b * NC + c0 + c] = v[8];
    }
    if (t == 0) {
        ws[WS_SX2P + bid] = accw[0][0] + accw[0][1] + accw[0][2] + accw[0][3];
        ws[WS_UUP + bid]  = accw[1][0] + accw[1][1] + accw[1][2] + accw[1][3];
    }
}

// ksv: Sv/Sve matvec + per-block T1/T2 partials for d2
__global__ void ksv(const float* __restrict__ Wv, const float* __restrict__ bv,
                    const float* __restrict__ Wc, const float* __restrict__ bq,
                    const float* __restrict__ bk, float* __restrict__ ws) {
    const int bid = blockIdx.x;          // 64: b*8 + oc
    const int b = bid >> 3, oc = bid & 7;
    const int t = threadIdx.x;           // 256
    const int o_sub = t >> 3, ks = t & 7;
    const int o = oc * 32 + o_sub;
    __shared__ float sxl[NC], xel[NC];
    __shared__ float T1s[32], T2s[32];
    __shared__ float s_cq, s_ck;
    if (t < 64) {
        float p = Wc[t] * bq[t], rr = Wc[64 + t] * bk[t];
        for (int off = 32; off > 0; off >>= 1) {
            p += __shfl_down(p, off, 64);
            rr += __shfl_down(rr, off, 64);
        }
        if (t == 0) { s_cq = p; s_ck = rr; }
    }
    sxl[t] = ws[WS_SX + b * NC + t];
    xel[t] = ws[WS_XE + b * NC + t];
    __syncthreads();
    const float Seq  = ws[WS_MOM2 + b * 4 + 0];
    const float Sek  = ws[WS_MOM2 + b * 4 + 1];
    const float Sek2 = ws[WS_MOM2 + b * 4 + 2];
    const float cq = s_cq, ck = s_ck;
    float wsx = 0.f, wxe = 0.f;
    const float4* wrow = (const float4*)(Wv + (size_t)o * NC);
#pragma unroll
    for (int i = 0; i < 8; ++i) {
        float4 w4 = wrow[i * 8 + ks];
        int k = i * 32 + ks * 4;
        wsx += w4.x * sxl[k] + w4.y * sxl[k + 1] + w4.z * sxl[k + 2] + w4.w * sxl[k + 3];
        wxe += w4.x * xel[k] + w4.y * xel[k + 1] + w4.z * xel[k + 2] + w4.w * xel[k + 3];
    }
    for (int off = 4; off > 0; off >>= 1) {
        wsx += __shfl_down(wsx, off, 8);
        wxe += __shfl_down(wxe, off, 8);
    }
    if (ks == 0) {
        float bvc = bv[o];
        float Sv  = wsx + (float)NN * bvc;
        float SvL = wsx;
        float Sve = wxe + bvc * Seq;
        float* st = ws + WS_STAT + b * STAT_STRIDE;
        st[ST_SV + o] = Sv; st[ST_SVE + o] = Sve;
        float A = 2.f * Sve - bvc * Seq - cq * Sv;
        float sx = sxl[o];
        float xk = ws[WS_XK + b * NC + o];
        float xkL = xk - ck * sx;
        float T1c = A * sx + Sv * xkL + SvL * xk;
        float SP  = Sek - (float)NN * ck;
        float SP2 = Sek2 - 2.f * ck * Sek + (float)NN * ck * ck;
        float SPQ = Sek2 - ck * Sek;
        float T2c = (float)NN * A * A + Sv * Sv * SP2 + SvL * SvL * Sek2
                  + 2.f * A * Sv * SP + 2.f * A * SvL * Sek + 2.f * Sv * SvL * SPQ;
        T1s[o_sub] = T1c; T2s[o_sub] = T2c;
    }
    __syncthreads();
    if (t == 0) {
        float t1 = 0.f, t2 = 0.f;
        for (int i = 0; i < 32; ++i) { t1 += T1s[i]; t2 += T2s[i]; }
        ws[WS_T1P + bid] = t1;
        ws[WS_T2P + bid] = t2;
    }
}

// kfin: blocks 0..7 = recursion via MFMA (r15/r17 verified); 8..519 = output-0.
struct KFSMem {
    unsigned int Wlds[32768];               // 128KB W^T bf16, swizzled
    unsigned int Vsb[128] __attribute__((aligned(16)));
    unsigned int Veb[128] __attribute__((aligned(16)));
    float P_lds[256];
    float R_lds[256];
    float dred[9][4];
    float gred0[4];
    float gredT[2];
    float sge;
};

__global__ void __launch_bounds__(1024, 4) kfin(
        const float* __restrict__ x, const float* __restrict__ bv,
        const float* __restrict__ gamma, float* __restrict__ ws,
        float* __restrict__ out) {
    __shared__ __align__(16) unsigned char smem_raw[sizeof(KFSMem)];
    KFSMem& S = *(KFSMem*)smem_raw;
    const int bid = blockIdx.x;      // 520
    const int t = threadIdx.x;       // 1024
    const int lane = t & 63;
    const bool is_iter = (bid < 8);
    uint4 stg0, stg1, stg2, stg3, stg4, stg5, stg6, stg7;
    if (is_iter) {
        const uint4* wvb4 = (const uint4*)((const unsigned int*)ws + WS_WVB);
        stg0 = wvb4[0 * 1024 + t]; stg1 = wvb4[1 * 1024 + t];
        stg2 = wvb4[2 * 1024 + t]; stg3 = wvb4[3 * 1024 + t];
        stg4 = wvb4[4 * 1024 + t]; stg5 = wvb4[5 * 1024 + t];
        stg6 = wvb4[6 * 1024 + t]; stg7 = wvb4[7 * 1024 + t];
    }
    {
        float a = 0.f, b1 = 0.f, c1 = 0.f;
        if (t < 256) a = ws[WS_SX2P + t];
        if (t < 64) { b1 = ws[WS_T1P + t]; c1 = ws[WS_T2P + t]; }
        for (int off = 32; off > 0; off >>= 1) {
            a  += __shfl_down(a,  off, 64);
            b1 += __shfl_down(b1, off, 64);
            c1 += __shfl_down(c1, off, 64);
        }
        if (t < 256 && lane == 0) S.gred0[t >> 6] = a;
        if (t == 0) { S.gredT[0] = b1; S.gredT[1] = c1; }
    }
    __syncthreads();
    if (t == 0) {
        float S1 = S.gred0[0] + S.gred0[1] + S.gred0[2] + S.gred0[3];
        float inv = gamma[0] * (1.f / (float)NN);
        float dd = S1 + 2.f * inv * S.gredT[0] + inv * inv * S.gredT[1];
        float lip = sqrtf(dd / S1);
        S.sge = gamma[0] * ((lip > 0.9f) ? (0.9f / lip) : 1.f);
    }
    __syncthreads();
    const float ge = S.sge;

    if (!is_iter) {
        const float gn = ge * (1.f / (float)NN);
        const int r = t >> 8, tc = t & 255;
        const int bid2 = (bid - 8) * 4 + r;
        const int b = bid2 >> 8, c = bid2 & 255;
        const float* st = ws + WS_STAT + b * STAT_STRIDE;
        float sv = st[ST_SV + c], sve = st[ST_SVE + c];
        float4 ek4 = ((const float4*)(st + ST_EK))[tc];
        size_t i4 = (size_t)bid2 * 256 + tc;
        float4 x4 = ((const float4*)x)[i4];
        float4 o;
        o.x = 2.f * x4.x + gn * (sve + ek4.x * sv);
        o.y = 2.f * x4.y + gn * (sve + ek4.y * sv);
        o.z = 2.f * x4.z + gn * (sve + ek4.z * sv);
        o.w = 2.f * x4.w + gn * (sve + ek4.w * sv);
        ((float4*)out)[i4] = o;
        return;
    }

    const int b = bid;
    const int nt = t >> 6;
    const int row = lane & 15;
    const int kgrp = lane >> 4;
    const int o = nt * 16 + row;
    const int wid4 = (t & 255) >> 6;
    ((uint4*)S.Wlds)[0 * 1024 + t] = stg0; ((uint4*)S.Wlds)[1 * 1024 + t] = stg1;
    ((uint4*)S.Wlds)[2 * 1024 + t] = stg2; ((uint4*)S.Wlds)[3 * 1024 + t] = stg3;
    ((uint4*)S.Wlds)[4 * 1024 + t] = stg4; ((uint4*)S.Wlds)[5 * 1024 + t] = stg5;
    ((uint4*)S.Wlds)[6 * 1024 + t] = stg6; ((uint4*)S.Wlds)[7 * 1024 + t] = stg7;
    const float s = ge * (1.f / (float)NN);
    float Svl_r = 0.f, sxl_r = 0.f, xkl_r = 0.f, caql_r = 0.f, cakl_r = 0.f,
          Uel_r = 0.f, Vsul_r = 0.f, bvl_r = 0.f, aql_r = 0.f, akl_r = 0.f,
          veu_r = 0.f, cuak_r = 0.f, vsreg = 0.f, vereg = 0.f;
    if (t < 256) {
        const float* st = ws + WS_STAT + b * STAT_STRIDE;
        Svl_r  = st[ST_SV + t];
        sxl_r  = ws[WS_SX   + b * NC + t];
        xkl_r  = ws[WS_XK   + b * NC + t];
        caql_r = ws[WS_CAQ  + b * NC + t];
        cakl_r = ws[WS_CAK  + b * NC + t];
        Uel_r  = ws[WS_UE   + b * NC + t];
        Vsul_r = ws[WS_VSU  + b * NC + t];
        veu_r  = ws[WS_VEU  + b * NC + t];
        cuak_r = ws[WS_CUAK + b * NC + t];
        aql_r  = ws[WS_AQ + t];
        akl_r  = ws[WS_AK + t];
        bvl_r  = bv[t];
        vsreg = Vsul_r; vereg = veu_r;
        float vs_o = __shfl_xor(vsreg, 1, 64);
        float ve_o = __shfl_xor(vereg, 1, 64);
        if ((t & 1) == 0) {
            S.Vsb[t >> 1] = bf16lo(vsreg) | bf16hi(vs_o);
            S.Veb[t >> 1] = bf16lo(vereg) | bf16hi(ve_o);
        }
    }
    const float Seq  = ws[WS_MOM2 + b * 4 + 0];
    const float Sek  = ws[WS_MOM2 + b * 4 + 1];
    const float Sekq = ws[WS_MOM2 + b * 4 + 3];
    float uu = 0.f;
    for (int g = 0; g < 32; ++g) uu += ws[WS_UUP + b * 32 + g];
    __syncthreads();
    if (t < 256) {
        float d[8] = {Svl_r * cuak_r, aql_r * Vsul_r, akl_r * Vsul_r, akl_r * Uel_r,
                      Svl_r * Vsul_r, Svl_r * veu_r,  Svl_r * aql_r,  Svl_r * akl_r};
        for (int off = 32; off > 0; off >>= 1)
            for (int m = 0; m < 8; ++m) d[m] += __shfl_down(d[m], off, 64);
        if (lane == 0) for (int m = 0; m < 8; ++m) S.dred[m][wid4] = d[m];
    }
    __syncthreads();
    float g2a = 0.f, aqVsu = 0.f, akVsu = 0.f, akUe = 0.f, SvVsu = 0.f, SvVeu = 0.f,
          Svaq = 0.f, Svak = 0.f;
    if (t < 256) {
        g2a   = S.dred[0][0] + S.dred[0][1] + S.dred[0][2] + S.dred[0][3];
        aqVsu = S.dred[1][0] + S.dred[1][1] + S.dred[1][2] + S.dred[1][3];
        akVsu = S.dred[2][0] + S.dred[2][1] + S.dred[2][2] + S.dred[2][3];
        akUe  = S.dred[3][0] + S.dred[3][1] + S.dred[3][2] + S.dred[3][3];
        SvVsu = S.dred[4][0] + S.dred[4][1] + S.dred[4][2] + S.dred[4][3];
        SvVeu = S.dred[5][0] + S.dred[5][1] + S.dred[5][2] + S.dred[5][3];
        Svaq  = S.dred[6][0] + S.dred[6][1] + S.dred[6][2] + S.dred[6][3];
        Svak  = S.dred[7][0] + S.dred[7][1] + S.dred[7][2] + S.dred[7][3];
    }
    __syncthreads();
    const float lam = 1.f + s * Svak;
    float alpha = 1.f, beta = 0.f, gam = 0.f;
    float SxAcc = 0.f, XkAcc = 0.f, CakAcc = 0.f;
    float dot = uu, tr = 0.f;
    const float coef[5] = {1.f, -0.5f, 1.f / 3.f, -0.25f, 0.2f};
    const uint4* Vsb4 = (const uint4*)S.Vsb;
    const uint4* Veb4 = (const uint4*)S.Veb;
    const uint4* Wlds4 = (const uint4*)S.Wlds;
    for (int j = 0; j < 5; ++j) {
        f32x4 acc = {0.f, 0.f, 0.f, 0.f};
#pragma unroll
        for (int kc = 0; kc < 8; ++kc) {
            const uint4* asrc = (row == 1) ? Veb4 : Vsb4;
            uint4 araw = asrc[kc * 4 + kgrp];
            if (row >= 2) { araw.x = 0u; araw.y = 0u; araw.z = 0u; araw.w = 0u; }
            FragU fa; fa.u = araw;
            FragU fb; fb.u = Wlds4[o * 32 + ((kc * 4 + kgrp) ^ (o & 7))];
            acc = __builtin_amdgcn_mfma_f32_16x16x32_bf16(fa.h, fb.h, acc, 0, 0, 0);
        }
        if (lane < 16) {
            S.P_lds[nt * 16 + lane] = acc[0];
            S.R_lds[nt * 16 + lane] = acc[1];
        }
        __syncthreads();
        if (t < 256) {
            float Pv = s * S.P_lds[t];
            float Rv = s * S.R_lds[t];
            float d[9];
            d[0] = Svl_r * Pv;
            d[1] = Svl_r * Rv;
            d[2] = bvl_r * vsreg;
            d[3] = sxl_r * Pv;
            d[4] = xkl_r * Pv;
            d[5] = caql_r * Pv;
            d[6] = cakl_r * Pv;
            d[7] = Uel_r * Pv;
            d[8] = Vsul_r * Rv;
            for (int off = 32; off > 0; off >>= 1)
                for (int m = 0; m < 9; ++m) d[m] += __shfl_down(d[m], off, 64);
            if (lane == 0) for (int m = 0; m < 9; ++m) S.dred[m][wid4] = d[m];
        }
        __syncthreads();
        if (t < 256) {
            float Pv = s * S.P_lds[t];
            float Rv = s * S.R_lds[t];
            float sm[9];
            for (int m = 0; m < 9; ++m)
                sm[m] = S.dred[m][0] + S.dred[m][1] + S.dred[m][2] + S.dred[m][3];
            const float svP = sm[0], svR = sm[1], bvVs = sm[2], sxP = sm[3], xkP = sm[4],
                        caqP = sm[5], cakP = sm[6], ueP = sm[7], vsuR = sm[8];
            const float sB = s * bvVs;
            float St  = s * (alpha * SvVsu + beta * (float)NN + gam * Seq  + Svaq * SxAcc);
            float tek = s * (alpha * SvVeu + beta * Sek        + gam * Sekq + Svaq * XkAcc);
            float uta = s * (alpha * g2a   + beta * akVsu      + gam * akUe + Svaq * CakAcc);
            dot += ueP + caqP + sB * aqVsu + uta + vsuR;
            tr  += coef[j] * dot;
            float nVs = vsreg + Pv * Seq  + aql_r * (sxP + (float)NN * sB) + akl_r * St  + Rv * (float)NN;
            float nVe = vereg + Pv * Sekq + aql_r * (xkP + sB * Sek)       + akl_r * tek + Rv * Sek;
            vsreg = nVs; vereg = nVe;
            float vs_o = __shfl_xor(nVs, 1, 64);
            float ve_o = __shfl_xor(nVe, 1, 64);
            if ((t & 1) == 0) {
                S.Vsb[t >> 1] = bf16lo(nVs) | bf16hi(vs_o);
                S.Veb[t >> 1] = bf16lo(nVe) | bf16hi(ve_o);
            }
            SxAcc  = lam * SxAcc  + sxP;
            XkAcc  = lam * XkAcc  + xkP;
            CakAcc = lam * CakAcc + cakP;
            beta = lam * beta + Svaq * sB + svR;
            gam  = lam * gam + svP;
            alpha *= lam;
        }
        __syncthreads();
    }
    if (t == 0) out[2097152 + b] = tr;
}

extern "C" void kernel_launch(void* const* d_in, const int* in_sizes, int n_in,
                              void* d_out, int out_size, void* d_ws, size_t ws_size,
                              hipStream_t stream) {
    const float* x     = (const float*)d_in[0];
    const float* Wq    = (const float*)d_in[1];
    const float* bq    = (const float*)d_in[2];
    const float* Wk    = (const float*)d_in[3];
    const float* bk    = (const float*)d_in[4];
    const float* Wc    = (const float*)d_in[5];
    const float* Wv    = (const float*)d_in[6];
    const float* bv    = (const float*)d_in[7];
    const float* gamma = (const float*)d_in[8];
    const float* u     = (const float*)d_in[9];
    float* out = (float*)d_out;
    float* ws  = (float*)d_ws;

    kA  <<<dim3(260), dim3(256),  0, stream>>>(x, u, Wq, Wk, Wc, Wv, ws);
    kB  <<<dim3(256), dim3(256),  0, stream>>>(x, u, Wc, bq, bk, ws);
    ksv <<<dim3(64),  dim3(256),  0, stream>>>(Wv, bv, Wc, bq, bk, ws);
    kfin<<<dim3(520), dim3(1024), 0, stream>>>(x, bv, gamma, ws, out);
}